// Round 4
// baseline (711.587 us; speedup 1.0000x reference)
//
#include <hip/hip_runtime.h>
#include <stdint.h>

typedef unsigned short u16;
typedef short v8s __attribute__((ext_vector_type(8)));
typedef short v4s __attribute__((ext_vector_type(4)));
typedef float v4f __attribute__((ext_vector_type(4)));

#define NB 32768
#define ND 256
#define DTF (1.0f/3.0f)
#define ALPHA 0.1f
#define DECAY 0.99f
#define TAU_MIN 0.2f
#define HEBB_SCALE (0.1f*(1.0f/3.0f)/32768.0f)

__device__ __forceinline__ float b2f(u16 h){ return __uint_as_float(((unsigned)h)<<16); }
__device__ __forceinline__ u16 f2b(float f){
  unsigned u = __float_as_uint(f);
  u += 0x7FFFu + ((u>>16)&1u);
  return (u16)(u>>16);
}

__device__ __forceinline__ void async16(const void* g, void* l){
  __builtin_amdgcn_global_load_lds((const __attribute__((address_space(1))) unsigned*)g,
                                   (__attribute__((address_space(3))) unsigned*)l, 16, 0, 0);
}

__device__ __forceinline__ void waitv(int n){
  switch(n){
    case 9: asm volatile("s_waitcnt vmcnt(9)" ::: "memory"); break;
    case 8: asm volatile("s_waitcnt vmcnt(8)" ::: "memory"); break;
    case 7: asm volatile("s_waitcnt vmcnt(7)" ::: "memory"); break;
    case 6: asm volatile("s_waitcnt vmcnt(6)" ::: "memory"); break;
    case 4: asm volatile("s_waitcnt vmcnt(4)" ::: "memory"); break;
    case 2: asm volatile("s_waitcnt vmcnt(2)" ::: "memory"); break;
    default: asm volatile("s_waitcnt vmcnt(0)" ::: "memory"); break;
  }
}

// ---------------- init: x,h -> bf16 copies, h -> f32 state ----------------
__global__ void k_copy(const float* __restrict__ x, const float* __restrict__ h,
                       u16* __restrict__ x_bf, u16* __restrict__ h_bf,
                       float* __restrict__ h_state){
  const long tot = (long)NB*ND/4;
  for (long i = blockIdx.x*(long)blockDim.x + threadIdx.x; i < tot;
       i += (long)gridDim.x*blockDim.x){
    v4f xv = *(const v4f*)(x + 4*i);
    v4f hv = *(const v4f*)(h + 4*i);
    u16 t4[4], t5[4];
#pragma unroll
    for (int e=0;e<4;++e){ t4[e] = f2b(xv[e]); t5[e] = f2b(hv[e]); }
    *(v4s*)(x_bf + 4*i) = *(v4s*)t4;
    *(v4s*)(h_bf + 4*i) = *(v4s*)t5;
    *(v4f*)(h_state + 4*i) = hv;
  }
}

// ---------------- x -> xT (bf16, [i][b]) ----------------
__global__ void k_transpose_x(const float* __restrict__ x, u16* __restrict__ xT){
  __shared__ u16 ld[64*65];
  int bt = blockIdx.x >> 2, it = blockIdx.x & 3;
  long b0 = (long)bt*64; int i0 = it*64;
  int t = threadIdx.x;
#pragma unroll
  for (int e=0;e<16;++e){
    int idx = e*256 + t; int r = idx>>6, c = idx&63;
    ld[c + r*65] = f2b(x[(b0+r)*ND + i0 + c]);
  }
  __syncthreads();
#pragma unroll
  for (int e=0;e<16;++e){
    int idx = e*256 + t; int rr = idx>>6, cc = idx&63;
    xT[(long)(i0+rr)*NB + b0 + cc] = ld[cc*65 + rr];
  }
}

// ---------------- weight prep (bf16 [n][k]) ----------------
__global__ void k_prep_w(const float* __restrict__ W_ih, const float* __restrict__ W_hh,
                         const float* __restrict__ W_t1, const float* __restrict__ W_t2,
                         const float* __restrict__ hebb_ih, const float* __restrict__ hebb_hh,
                         u16* __restrict__ weff_ih, u16* __restrict__ weff_hh,
                         u16* __restrict__ wt1a, u16* __restrict__ wt1b, u16* __restrict__ wt2){
  int i = blockIdx.x*blockDim.x + threadIdx.x;
  if (i >= ND*ND) return;
  int n = i >> 8, k = i & 255;
  weff_ih[i] = f2b(W_ih[i] + ALPHA*hebb_ih[k*ND + n]);
  weff_hh[i] = f2b(W_hh[i] + ALPHA*hebb_hh[k*ND + n]);
  wt1a[i] = f2b(W_t1[n*512 + k]);
  wt1b[i] = f2b(W_t1[n*512 + 256 + k]);
  wt2[i]  = f2b(W_t2[i]);
}

// ---------------- P = x @ W_t1a^T + b_t1  (bf16 out) ----------------
__launch_bounds__(512,2)
__global__ void k_gemmP(const u16* __restrict__ x_bf, const u16* __restrict__ wt1a,
                        const float* __restrict__ b_t1, u16* __restrict__ P){
  __shared__ u16 lA[128*40];
  __shared__ u16 lB[256*40];
  int t = threadIdx.x, lid = t&63, wid = t>>6, wm = wid>>2, wn = wid&3, lr = lid&15, lg = lid>>4;
  long row0 = (long)blockIdx.x*128;
  v4f z = {0.f,0.f,0.f,0.f};
  v4f acc[4][4];
#pragma unroll
  for (int a=0;a<4;++a)
#pragma unroll
    for (int b=0;b<4;++b) acc[a][b] = z;
  for (int c=0; c<8; ++c){
    __syncthreads();
    { int r=t>>2, sg=t&3;
      *(v8s*)&lA[r*40+sg*8] = *(const v8s*)(x_bf + (row0+r)*ND + c*32 + sg*8); }
#pragma unroll
    for (int it2=0; it2<2; ++it2){
      int s2=t+it2*512; int n=s2>>2, sg=s2&3;
      *(v8s*)&lB[n*40+sg*8] = *(const v8s*)(wt1a + n*ND + c*32 + sg*8);
    }
    __syncthreads();
    v8s a[4], b[4];
#pragma unroll
    for (int mf=0;mf<4;++mf) a[mf] = *(v8s*)&lA[(wm*64+mf*16+lr)*40 + lg*8];
#pragma unroll
    for (int nf=0;nf<4;++nf) b[nf] = *(v8s*)&lB[(wn*64+nf*16+lr)*40 + lg*8];
#pragma unroll
    for (int mf=0;mf<4;++mf)
#pragma unroll
      for (int nf=0;nf<4;++nf)
        acc[mf][nf] = __builtin_amdgcn_mfma_f32_16x16x32_bf16(a[mf], b[nf], acc[mf][nf], 0,0,0);
  }
#pragma unroll
  for (int mf=0;mf<4;++mf)
#pragma unroll
    for (int nf=0;nf<4;++nf)
#pragma unroll
      for (int r=0;r<4;++r){
        int rr = wm*64+mf*16+lg*4+r, cc = wn*64+nf*16+lr;
        P[(row0+rr)*ND + cc] = f2b(acc[mf][nf][r] + b_t1[cc]);
      }
}

// ---------------- fused dynamics + RK update (deep-pipelined) ----------------
// jobs 0-7:  ev @ wt1b    -> acc2   (t1 pre-act)
// jobs 8-15: x  @ weff_ih -> accI
// jobs 16-23:ev @ weff_hh -> accI
// jobs 24-31: u @ wt2     -> acc4   (u from LDS, built at job-7 boundary)
template<int BASEF, int WF, int WT>
__launch_bounds__(512,2)
__global__ void k_dyn2(const u16* __restrict__ x_bf, const u16* __restrict__ ev_bf,
                       const float* __restrict__ baseF,
                       const u16* __restrict__ weff_ih, const u16* __restrict__ weff_hh,
                       const u16* __restrict__ wt1b, const u16* __restrict__ wt2,
                       const u16* __restrict__ P,
                       const float* __restrict__ b_ih, const float* __restrict__ b_hh,
                       const float* __restrict__ b_t2, float coef,
                       float* __restrict__ outF, u16* __restrict__ outB, u16* __restrict__ outT){
  __shared__ u16 lA[5*64*32];      // 5-slot ring, [64][32] linear (gload_lds dest)
  __shared__ u16 lB[5*256*32];     // 5-slot ring, [256][32] linear
  __shared__ u16 lU[64*296];       // u panel [64][296]; reused as [256][72] for transpose-out
  __shared__ float sb1[256], sb2[256];
  const int t = threadIdx.x, lid = t&63, wid = t>>6;
  const int wm = wid>>2, wn = wid&3, lr = lid&15, lg = lid>>4;
  const long row0 = (long)blockIdx.x*64;

  if (t < 256){ sb1[t] = b_ih[t] + b_hh[t]; sb2[t] = b_t2[t]; }

  // staging source offsets (XOR-swizzled chunk: stored j' holds global chunk j'^s(row))
  const int rA  = (wid&3)*16 + (lid>>2);
  const int scA = (lid&3) ^ ((rA>>1)&3);
  const long aoffg = (row0 + rA)*ND + scA*8;            // + c*32
  const int rB0 = wid*32 + (lid>>2), rB1 = rB0 + 16;
  const int boffg0 = rB0*ND + (((lid&3) ^ ((rB0>>1)&3))*8);
  const int boffg1 = rB1*ND + (((lid&3) ^ ((rB1>>1)&3))*8);

  // fragment read offsets (u16 index within a slot)
  int aoff[2], boff[4], uoffb[2];
#pragma unroll
  for (int mf=0;mf<2;++mf){
    int R = wm*32 + mf*16 + lr;
    aoff[mf] = R*32 + ((lg ^ ((R>>1)&3))*8);
    uoffb[mf] = R*296 + lg*8;
  }
#pragma unroll
  for (int nf=0;nf<4;++nf){
    int N = wn*64 + nf*16 + lr;
    boff[nf] = N*32 + ((lg ^ ((N>>1)&3))*8);
  }

  // P prefetch (registers; drained at prologue barrier)
  u16 Pv[32];
#pragma unroll
  for (int mf=0;mf<2;++mf)
#pragma unroll
    for (int nf=0;nf<4;++nf)
#pragma unroll
      for (int r=0;r<4;++r){
        int rr = wm*32+mf*16+lg*4+r, cc = wn*64+nf*16+lr;
        Pv[(mf*4+nf)*4+r] = P[(row0+rr)*ND + cc];
      }

  // stage helpers -------------------------------------------------------
  auto stageA = [&](int jj){               // waves 0-3 only; jobs 0..23
    if (wid < 4){
      const u16* src = (jj < 8) ? ev_bf : (jj < 16 ? x_bf : ev_bf);
      async16(src + aoffg + (jj&7)*32, lA + (jj%5)*2048 + (wid&3)*512);
    }
  };
  auto stageB = [&](int jj){               // all waves
    const u16* W = (jj<8) ? wt1b : (jj<16 ? weff_ih : (jj<24 ? weff_hh : wt2));
    int c = (jj&7)*32;
    async16(W + c + boffg0, lB + (jj%5)*8192 + wid*1024);
    async16(W + c + boffg1, lB + (jj%5)*8192 + wid*1024 + 512);
  };

  // prologue: jobs 0-3 staged, then full drain
  stageB(0); stageA(0);
  stageB(1); stageA(1);
  stageB(2); stageA(2);
  stageB(3); stageA(3);
  __syncthreads();                          // vmcnt(0)+lgkmcnt(0)+barrier

  v4f z = {0.f,0.f,0.f,0.f};
  v4f acc2[2][4], accI[2][4], acc4[2][4];
#pragma unroll
  for (int a=0;a<2;++a)
#pragma unroll
    for (int b=0;b<4;++b){ acc2[a][b]=z; accI[a][b]=z; acc4[a][b]=z; }

#pragma unroll
  for (int j=0; j<32; ++j){
    // counted wait: A+B(j) landed; 4-iter-lead loads stay in flight
    int n;
    if (wid < 4) n = (j<=20)?9:((j==21)?8:((j==22)?7:((j<=28)?6:((j==29)?4:((j==30)?2:0)))));
    else         n = (j<=28)?6:((j==29)?4:((j==30)?2:0));
    waitv(n);
    __builtin_amdgcn_s_barrier();
    if (j <= 19) stageA(j+4);
    if (j <= 27) stageB(j+4);

    v8s b[4];
#pragma unroll
    for (int nf=0;nf<4;++nf) b[nf] = *(v8s*)&lB[(j%5)*8192 + boff[nf]];

    if (j < 24){
      v8s a[2];
#pragma unroll
      for (int mf=0;mf<2;++mf) a[mf] = *(v8s*)&lA[(j%5)*2048 + aoff[mf]];
      if (j < 8){
#pragma unroll
        for (int mf=0;mf<2;++mf)
#pragma unroll
          for (int nf=0;nf<4;++nf)
            acc2[mf][nf] = __builtin_amdgcn_mfma_f32_16x16x32_bf16(a[mf], b[nf], acc2[mf][nf], 0,0,0);
      } else {
#pragma unroll
        for (int mf=0;mf<2;++mf)
#pragma unroll
          for (int nf=0;nf<4;++nf)
            accI[mf][nf] = __builtin_amdgcn_mfma_f32_16x16x32_bf16(a[mf], b[nf], accI[mf][nf], 0,0,0);
      }
    } else {
      v8s a[2];
#pragma unroll
      for (int mf=0;mf<2;++mf) a[mf] = *(v8s*)&lU[uoffb[mf] + (j-24)*32];
#pragma unroll
      for (int mf=0;mf<2;++mf)
#pragma unroll
        for (int nf=0;nf<4;++nf)
          acc4[mf][nf] = __builtin_amdgcn_mfma_f32_16x16x32_bf16(a[mf], b[nf], acc4[mf][nf], 0,0,0);
    }

    if (j == 7){
      // u = SiLU(acc2 + P) -> lU [64][296]
#pragma unroll
      for (int mf=0;mf<2;++mf)
#pragma unroll
        for (int nf=0;nf<4;++nf)
#pragma unroll
          for (int r=0;r<4;++r){
            int rr = wm*32+mf*16+lg*4+r, cc = wn*64+nf*16+lr;
            float v = acc2[mf][nf][r] + b2f(Pv[(mf*4+nf)*4+r]);
            float sgm = 1.f/(1.f + __expf(-v));
            lU[rr*296 + cc] = f2b(v*sgm);
          }
      asm volatile("s_waitcnt lgkmcnt(0)" ::: "memory");
    }
  }

  __syncthreads();   // lU phase-3 reads done (before WT reuse)

  // epilogue: inter = tanh(accI + b), tau = softplus(acc4 + b_t2) + TAU_MIN
#pragma unroll
  for (int mf=0;mf<2;++mf)
#pragma unroll
    for (int nf=0;nf<4;++nf)
#pragma unroll
      for (int r=0;r<4;++r){
        int rr = wm*32+mf*16+lg*4+r, cc = wn*64+nf*16+lr;
        long gi = (row0+rr)*ND + cc;
        float pre = accI[mf][nf][r] + sb1[cc];
        float pc = fminf(fmaxf(pre, -15.f), 15.f);
        float e2 = __expf(2.f*pc);
        float inter = (e2 - 1.f)/(e2 + 1.f);
        float zz = acc4[mf][nf][r] + sb2[cc];
        float sp = (zz > 15.f) ? zz : __logf(1.f + __expf(zz));
        float tau = sp + TAU_MIN;
        float bv, ev;
        if (BASEF){ bv = baseF[gi]; ev = b2f(ev_bf[gi]); }
        else      { bv = b2f(ev_bf[gi]); ev = bv; }
        float o = bv + coef*(inter - ev)/tau;
        if (WF) outF[gi] = o;
        outB[gi] = f2b(o);
        if (WT) lU[cc*72 + rr] = f2b(o);
      }
  if (WT){
    __syncthreads();
    int cc = t>>1, r0 = (t&1)*32;
#pragma unroll
    for (int e=0;e<4;++e){
      v8s v = *(v8s*)&lU[cc*72 + r0 + e*8];
      *(v8s*)(outT + (long)cc*NB + row0 + r0 + e*8) = v;
    }
  }
}

// ---------------- hebb partial: part[blk] = A^T-chunk @ m-chunk ----------------
__launch_bounds__(512,2)
__global__ void k_hebb_part(const u16* __restrict__ xT, const u16* __restrict__ hmT,
                            u16* __restrict__ part){
  __shared__ u16 lA[256*40];
  __shared__ u16 lB[256*40];
  int t = threadIdx.x, lid = t&63, wid = t>>6, wm = wid>>2, wn = wid&3, lr = lid&15, lg = lid>>4;
  int mat = blockIdx.x & 1, chunk = blockIdx.x >> 1;     // 64 chunks x 2 mats
  const u16* Asrc = mat ? hmT : xT;
  v4f z = {0.f,0.f,0.f,0.f};
  v4f acc[8][4];
#pragma unroll
  for (int a=0;a<8;++a)
#pragma unroll
    for (int b=0;b<4;++b) acc[a][b] = z;
  for (int kc=0; kc<16; ++kc){
    long b0 = (long)chunk*512 + kc*32;
    __syncthreads();
#pragma unroll
    for (int it2=0; it2<2; ++it2){
      int s = t + it2*512; int rr = s>>2, sg = s&3;
      *(v8s*)&lA[rr*40+sg*8] = *(const v8s*)(Asrc + (long)rr*NB + b0 + sg*8);
      *(v8s*)&lB[rr*40+sg*8] = *(const v8s*)(hmT  + (long)rr*NB + b0 + sg*8);
    }
    __syncthreads();
    v8s a[8], b[4];
#pragma unroll
    for (int mf=0;mf<8;++mf) a[mf] = *(v8s*)&lA[(wm*128+mf*16+lr)*40 + lg*8];
#pragma unroll
    for (int nf=0;nf<4;++nf) b[nf] = *(v8s*)&lB[(wn*64+nf*16+lr)*40 + lg*8];
#pragma unroll
    for (int mf=0;mf<8;++mf)
#pragma unroll
      for (int nf=0;nf<4;++nf)
        acc[mf][nf] = __builtin_amdgcn_mfma_f32_16x16x32_bf16(a[mf], b[nf], acc[mf][nf], 0,0,0);
  }
  u16* dst = part + (long)blockIdx.x*65536;
#pragma unroll
  for (int mf=0;mf<8;++mf)
#pragma unroll
    for (int nf=0;nf<4;++nf)
#pragma unroll
      for (int r=0;r<4;++r){
        int i = wm*128+mf*16+lg*4+r, j = wn*64+nf*16+lr;
        dst[i*ND + j] = f2b(acc[mf][nf][r]);
      }
}

// ---------------- hebb reduce + Weff rebuild ----------------
__global__ void k_hebb_reduce(const u16* __restrict__ part,
                              const float* __restrict__ prev_ih, const float* __restrict__ prev_hh,
                              float* __restrict__ next_ih, float* __restrict__ next_hh,
                              const float* __restrict__ W_ih, const float* __restrict__ W_hh,
                              u16* __restrict__ weff_ih, u16* __restrict__ weff_hh){
  int tid = blockIdx.x*blockDim.x + threadIdx.x;
  if (tid >= 2*ND*ND) return;
  int mat = tid >> 16;
  int rem = tid & 65535;
  float s = 0.f;
  for (int c=0; c<64; ++c) s += b2f(part[(long)((c<<1)+mat)*65536 + rem]);
  const float* prev = mat ? prev_hh : prev_ih;
  float nv = DECAY*prev[rem] + HEBB_SCALE*s;
  if (mat) next_hh[rem] = nv; else next_ih[rem] = nv;
  int k = rem >> 8, n = rem & 255;
  const float* Wb = mat ? W_hh : W_ih;
  u16 wv = f2b(Wb[n*ND + k] + ALPHA*nv);
  if (mat) weff_hh[n*ND + k] = wv; else weff_ih[n*ND + k] = wv;
}

// ---------------- launcher ----------------
extern "C" void kernel_launch(void* const* d_in, const int* in_sizes, int n_in,
                              void* d_out, int out_size, void* d_ws, size_t ws_size,
                              hipStream_t stream) {
  const float* x       = (const float*)d_in[0];
  const float* h       = (const float*)d_in[1];
  const float* hebb_ih = (const float*)d_in[2];
  const float* hebb_hh = (const float*)d_in[3];
  const float* W_ih    = (const float*)d_in[4];
  const float* b_ih    = (const float*)d_in[5];
  const float* W_hh    = (const float*)d_in[6];
  const float* b_hh    = (const float*)d_in[7];
  const float* W_t1    = (const float*)d_in[8];
  const float* b_t1    = (const float*)d_in[9];
  const float* W_t2    = (const float*)d_in[10];
  const float* b_t2    = (const float*)d_in[11];
  float* h_state = (float*)d_out;

  char* w = (char*)d_ws;
  u16* x_bf  = (u16*)w;  w += 16777216;
  u16* xT    = (u16*)w;  w += 16777216;
  u16* P     = (u16*)w;  w += 16777216;
  u16* hmT   = (u16*)w;  w += 16777216;
  u16* h_bf  = (u16*)w;  w += 16777216;
  u16* hm_bf = (u16*)w;  w += 16777216;
  u16* part  = (u16*)w;  w += 16777216;     // 128 slabs x 64K x 2B
  float* hebA_ih = (float*)w; w += 262144;
  float* hebA_hh = (float*)w; w += 262144;
  float* hebB_ih = (float*)w; w += 262144;
  float* hebB_hh = (float*)w; w += 262144;
  u16* weff_ih = (u16*)w; w += 131072;
  u16* weff_hh = (u16*)w; w += 131072;
  u16* wt1a    = (u16*)w; w += 131072;
  u16* wt1b    = (u16*)w; w += 131072;
  u16* wt2     = (u16*)w; w += 131072;
  if ((size_t)(w - (char*)d_ws) > ws_size) return;

  k_copy<<<2048,256,0,stream>>>(x, h, x_bf, h_bf, h_state);
  k_transpose_x<<<2048,256,0,stream>>>(x, xT);
  k_prep_w<<<256,256,0,stream>>>(W_ih,W_hh,W_t1,W_t2,hebb_ih,hebb_hh,
                                 weff_ih,weff_hh,wt1a,wt1b,wt2);
  k_gemmP<<<256,512,0,stream>>>(x_bf, wt1a, b_t1, P);

  const float* pih = hebb_ih; const float* phh = hebb_hh;
  for (int s=0; s<3; ++s){
    float* nih = (s&1) ? hebB_ih : hebA_ih;
    float* nhh = (s&1) ? hebB_hh : hebA_hh;
    // k1: h_mid = h + 0.5*DT*dynamics(h)   (bf16 state path; writes hm_bf + hmT)
    k_dyn2<0,0,1><<<512,512,0,stream>>>(x_bf, h_bf, h_state, weff_ih, weff_hh, wt1b, wt2, P,
                                        b_ih, b_hh, b_t2, 0.5f*DTF,
                                        (float*)0, hm_bf, hmT);
    // hebb updates + Weff rebuild
    k_hebb_part<<<128,512,0,stream>>>(xT, hmT, part);
    k_hebb_reduce<<<512,256,0,stream>>>(part, pih, phh, nih, nhh, W_ih, W_hh, weff_ih, weff_hh);
    // k2: h = h + DT*dynamics(h_mid)   (f32 state update in-place; writes h_bf for next k1)
    k_dyn2<1,1,0><<<512,512,0,stream>>>(x_bf, hm_bf, h_state, weff_ih, weff_hh, wt1b, wt2, P,
                                        b_ih, b_hh, b_t2, DTF,
                                        h_state, h_bf, (u16*)0);
    pih = nih; phh = nhh;
  }
}